// Round 2
// baseline (1390.550 us; speedup 1.0000x reference)
//
#include <hip/hip_runtime.h>
#include <hip/hip_bf16.h>

typedef __hip_bfloat16 bf16;
typedef __attribute__((ext_vector_type(4))) float f32x4;
typedef __attribute__((ext_vector_type(8))) unsigned short u16x8;
typedef __attribute__((ext_vector_type(4))) unsigned short u16x4;
typedef __bf16 bf16x8 __attribute__((ext_vector_type(8)));

#define NNODES 169
#define NNTOT  338
#define CH     256
#define NH     4
#define NL     3
#define SPAD   176
#define LN_EPS 1e-5f
#define GRIDBLK 256
#define SMEMB  30464   // max phase need: logits = 256f + 1024f + 32*176f + 4*176f

__device__ __forceinline__ float b2f(bf16 v) { return __bfloat162float(v); }
__device__ __forceinline__ float lrelu(float v) { return fmaxf(v, 0.2f * v); }
__device__ __forceinline__ float ldm(const void* p, size_t i, int isbf) {
    return isbf ? b2f(((const bf16*)p)[i]) : ((const float*)p)[i];
}
__device__ __forceinline__ int sniff_bf(const void* lng) {
    return ((((const unsigned*)lng)[0] & 0xFFFFu) == 0x3F80u) ? 1 : 0;
}
__device__ __forceinline__ unsigned short f2bf_rn(float f) {
    unsigned u = __float_as_uint(f);
    u += 0x7FFFu + ((u >> 16) & 1u);
    return (unsigned short)(u >> 16);
}
__device__ __forceinline__ float bfb2f(unsigned short h) {
    return __uint_as_float(((unsigned)h) << 16);
}

// ---------------------------------------------------------------- grid barrier
// 256 blocks on 256 CUs are trivially co-resident (>=1 block/CU capacity), so a
// plain launch + agent-scope atomic barrier is safe. Spin fuse prevents a hang
// if that assumption ever breaks (fails verification instead of timing out).
__device__ __forceinline__ void gbar(unsigned* cnt, unsigned* gen) {
    __syncthreads();
    if (threadIdx.x == 0) {
        __threadfence();   // release our data device-wide
        const unsigned g = __hip_atomic_load(gen, __ATOMIC_RELAXED, __HIP_MEMORY_SCOPE_AGENT);
        const unsigned a = __hip_atomic_fetch_add(cnt, 1u, __ATOMIC_ACQ_REL, __HIP_MEMORY_SCOPE_AGENT);
        if (a == GRIDBLK - 1) {
            __hip_atomic_store(cnt, 0u, __ATOMIC_RELAXED, __HIP_MEMORY_SCOPE_AGENT);
            __hip_atomic_fetch_add(gen, 1u, __ATOMIC_RELEASE, __HIP_MEMORY_SCOPE_AGENT);
        } else {
            long t = 0;
            while (__hip_atomic_load(gen, __ATOMIC_ACQUIRE, __HIP_MEMORY_SCOPE_AGENT) == g) {
                __builtin_amdgcn_s_sleep(2);
                if (++t > 5000000L) break;   // deadlock fuse (~0.5 s)
            }
        }
        __threadfence();   // acquire others' data
    }
    __syncthreads();
}

// ---------------------------------------------------------------- phase: W prep
// Transpose + bf16-hi/lo split of all weights into [L][N][K] hi/lo planes.
__device__ void wprep_phase(char* smemraw,
    const void* Wl, const void* Wr, const void* W1, const void* W2,
    unsigned short* wlT, unsigned short* wrT,
    unsigned short* w1T, unsigned short* w2T, int isbf)
{
    unsigned short* sH = (unsigned short*)smemraw;
    unsigned short* sL = sH + 64 * 72;
    const int tid = threadIdx.x;
    for (int vb = blockIdx.x; vb < 576; vb += GRIDBLK) {
        __syncthreads();
        int t = vb;
        const void* src; unsigned short* dst; int K, N;
        if (t < 384)      { K = 256; N = 1024; src = (t < 192) ? Wl : Wr;
                            dst = (t < 192) ? wlT : wrT; t = t % 192; }
        else if (t < 480) { K = 256; N = 512;  src = W1; dst = w1T; t -= 384; }
        else              { K = 512; N = 256;  src = W2; dst = w2T; t -= 480; }
        const int ntiles = N / 64;
        const int tpl = (K / 64) * ntiles;
        const int l = t / tpl; t %= tpl;
        const int k0 = (t / ntiles) * 64, n0 = (t % ntiles) * 64;
        const size_t loPlane = (size_t)NL * K * N;

        const int kk = tid >> 2, q = tid & 3;
        if (isbf) {
            const bf16* srow = (const bf16*)src + ((size_t)l * K + k0 + kk) * N + n0;
            #pragma unroll
            for (int i = 0; i < 4; i++) {
                const int c = q * 4 + i * 16;
                const int2 w = *(const int2*)(srow + c);
                sH[kk * 72 + c + 0] = (unsigned short)(w.x & 0xFFFF);
                sH[kk * 72 + c + 1] = (unsigned short)(((unsigned)w.x) >> 16);
                sH[kk * 72 + c + 2] = (unsigned short)(w.y & 0xFFFF);
                sH[kk * 72 + c + 3] = (unsigned short)(((unsigned)w.y) >> 16);
                sL[kk * 72 + c + 0] = 0; sL[kk * 72 + c + 1] = 0;
                sL[kk * 72 + c + 2] = 0; sL[kk * 72 + c + 3] = 0;
            }
        } else {
            const float* srow = (const float*)src + ((size_t)l * K + k0 + kk) * N + n0;
            #pragma unroll
            for (int i = 0; i < 4; i++) {
                const int c = q * 4 + i * 16;
                const float4 v4 = *(const float4*)(srow + c);
                const float vv[4] = { v4.x, v4.y, v4.z, v4.w };
                #pragma unroll
                for (int j = 0; j < 4; j++) {
                    const unsigned short h = f2bf_rn(vv[j]);
                    sH[kk * 72 + c + j] = h;
                    sL[kk * 72 + c + j] = f2bf_rn(vv[j] - bfb2f(h));
                }
            }
        }
        __syncthreads();
        for (int u = tid; u < 512; u += 256) {
            const int n = u >> 3, k8 = (u & 7) * 8;
            u16x8 hh, ll;
            #pragma unroll
            for (int j = 0; j < 8; j++) {
                hh[j] = sH[(k8 + j) * 72 + n];
                ll[j] = sL[(k8 + j) * 72 + n];
            }
            unsigned short* dh = dst + ((size_t)l * N + n0 + n) * K + k0 + k8;
            *(u16x8*)dh = hh;
            *(u16x8*)(dh + loPlane) = ll;
        }
    }
}

// ---------------------------------------------------------------- phase: MFMA GEMM tile
// C[338 x N] = A[338 x K] @ W + epilogue; bf16x3 split; tile 32x64, 4 waves.
// mode 0: +bias -> out (+ xlT scatter if xlT != null)
// mode 1: relu(+bias) -> out
// mode 2: +bias + residual -> out
__device__ void gemm_vb(char* smemraw, int m0, int n0,
    const void* A, int a_bf, int K, int N,
    const unsigned short* wH, const unsigned short* wL,
    const void* bias, size_t oB, int isbf,
    const void* res, int r_bf,
    float* out, float* xlT, int mode)
{
    unsigned short* sAh = (unsigned short*)smemraw;
    unsigned short* sAl = sAh + 32 * 40;
    unsigned short* sBh = sAl + 32 * 40;
    unsigned short* sBl = sBh + 64 * 40;
    const int tid = threadIdx.x;
    const int wave = tid >> 6, lane = tid & 63, l15 = lane & 15, g = lane >> 4;
    const int ar = tid >> 3, ak = (tid & 7) * 4;
    const int bn = tid >> 2, boct = tid & 3;

    f32x4 acc0 = {0.f, 0.f, 0.f, 0.f};
    f32x4 acc1 = {0.f, 0.f, 0.f, 0.f};
    const float* Af = (const float*)A;

    for (int k0 = 0; k0 < K; k0 += 32) {
        unsigned short h4[4] = {0, 0, 0, 0}, l4[4] = {0, 0, 0, 0};
        {
            const int grow = m0 + ar;
            if (grow < NNTOT) {
                const size_t ai = (size_t)grow * K + k0 + ak;
                if (a_bf) {
                    const int2 w = *(const int2*)((const bf16*)A + ai);
                    h4[0] = (unsigned short)(w.x & 0xFFFF);
                    h4[1] = (unsigned short)(((unsigned)w.x) >> 16);
                    h4[2] = (unsigned short)(w.y & 0xFFFF);
                    h4[3] = (unsigned short)(((unsigned)w.y) >> 16);
                } else {
                    const float4 t = *(const float4*)(Af + ai);
                    const float vv[4] = { t.x, t.y, t.z, t.w };
                    #pragma unroll
                    for (int j = 0; j < 4; j++) {
                        h4[j] = f2bf_rn(vv[j]);
                        l4[j] = f2bf_rn(vv[j] - bfb2f(h4[j]));
                    }
                }
            }
        }
        const size_t bi = (size_t)(n0 + bn) * K + k0 + boct * 8;
        const u16x8 bhv = *(const u16x8*)(wH + bi);
        const u16x8 blv = *(const u16x8*)(wL + bi);
        __syncthreads();
        {
            u16x4 ha, la;
            ha[0] = h4[0]; ha[1] = h4[1]; ha[2] = h4[2]; ha[3] = h4[3];
            la[0] = l4[0]; la[1] = l4[1]; la[2] = l4[2]; la[3] = l4[3];
            *(u16x4*)&sAh[ar * 40 + ak] = ha;
            *(u16x4*)&sAl[ar * 40 + ak] = la;
            *(u16x8*)&sBh[bn * 40 + boct * 8] = bhv;
            *(u16x8*)&sBl[bn * 40 + boct * 8] = blv;
        }
        __syncthreads();
        const bf16x8 a_h0 = *(const bf16x8*)&sAh[l15 * 40 + g * 8];
        const bf16x8 a_h1 = *(const bf16x8*)&sAh[(16 + l15) * 40 + g * 8];
        const bf16x8 a_l0 = *(const bf16x8*)&sAl[l15 * 40 + g * 8];
        const bf16x8 a_l1 = *(const bf16x8*)&sAl[(16 + l15) * 40 + g * 8];
        const bf16x8 b_h  = *(const bf16x8*)&sBh[(wave * 16 + l15) * 40 + g * 8];
        const bf16x8 b_l  = *(const bf16x8*)&sBl[(wave * 16 + l15) * 40 + g * 8];
        acc0 = __builtin_amdgcn_mfma_f32_16x16x32_bf16(a_h0, b_h, acc0, 0, 0, 0);
        acc1 = __builtin_amdgcn_mfma_f32_16x16x32_bf16(a_h1, b_h, acc1, 0, 0, 0);
        acc0 = __builtin_amdgcn_mfma_f32_16x16x32_bf16(a_l0, b_h, acc0, 0, 0, 0);
        acc1 = __builtin_amdgcn_mfma_f32_16x16x32_bf16(a_l1, b_h, acc1, 0, 0, 0);
        acc0 = __builtin_amdgcn_mfma_f32_16x16x32_bf16(a_h0, b_l, acc0, 0, 0, 0);
        acc1 = __builtin_amdgcn_mfma_f32_16x16x32_bf16(a_h1, b_l, acc1, 0, 0, 0);
    }

    const int col = n0 + wave * 16 + l15;
    const float bv = ldm(bias, oB + col, isbf);
    #pragma unroll
    for (int mi = 0; mi < 2; mi++) {
        const f32x4 a = mi ? acc1 : acc0;
        #pragma unroll
        for (int r = 0; r < 4; r++) {
            const int row = m0 + mi * 16 + g * 4 + r;
            if (row >= NNTOT) continue;
            float v = a[r] + bv;
            if (mode == 1) v = fmaxf(v, 0.f);
            if (mode == 2) v += ldm(res, (size_t)row * N + col, r_bf);
            out[(size_t)row * N + col] = v;
            if (mode == 0 && xlT) {
                const int hh = col >> 8, cc = col & 255;
                const int gg = (row >= NNODES) ? 1 : 0;
                const int ss = row - gg * NNODES;
                xlT[((size_t)(gg * NH + hh) * CH + cc) * SPAD + ss] = v;
            }
        }
    }
}

// ---------------------------------------------------------------- phase: logits+softmax
// 4 targets per vb; vb = (g, h, d-tile of 4). alphaR scaled by 0.25/z.
__device__ void logits_phase(char* smemraw,
    const float* xlT, const float* xr,
    const void* att, size_t oA, float* alphaR, int isbf)
{
    float* s_att  = (float*)smemraw;        // 256
    float* s_xr   = s_att + CH;             // 4*256
    float* s_tile = s_xr + 4 * CH;          // 32*176
    float* s_log  = s_tile + 32 * SPAD;     // 4*176
    const int tid = threadIdx.x, lane = tid & 63, wv = tid >> 6;

    for (int vb = blockIdx.x; vb < 344; vb += GRIDBLK) {
        const int g = vb / 172, rem = vb % 172, h = rem / 43, d0 = (rem % 43) * 4;
        __syncthreads();
        if (tid < CH) s_att[tid] = ldm(att, oA + h * CH + tid, isbf);
        for (int idx = tid; idx < 4 * CH; idx += 256) {
            const int i = idx >> 8, c = idx & 255, d = d0 + i;
            s_xr[idx] = (d < NNODES)
                ? xr[(size_t)(g * NNODES + d) * (NH * CH) + h * CH + c] : 0.f;
        }
        float l0 = 0.f, l1 = 0.f, l2 = 0.f, l3 = 0.f;
        const int s = tid;
        const float4* src = (const float4*)(xlT + ((size_t)(g * NH + h) * CH) * SPAD);
        for (int ch = 0; ch < 8; ch++) {
            __syncthreads();
            for (int i = tid; i < 32 * SPAD / 4; i += 256)
                ((float4*)s_tile)[i] = src[ch * (32 * SPAD / 4) + i];
            __syncthreads();
            if (s < NNODES) {
                const int cb = ch * 32;
                #pragma unroll
                for (int c = 0; c < 32; c++) {
                    const float v = s_tile[c * SPAD + s];
                    const float a = s_att[cb + c];
                    l0 += a * lrelu(v + s_xr[cb + c]);
                    l1 += a * lrelu(v + s_xr[CH + cb + c]);
                    l2 += a * lrelu(v + s_xr[2 * CH + cb + c]);
                    l3 += a * lrelu(v + s_xr[3 * CH + cb + c]);
                }
            }
        }
        if (s < NNODES) {
            s_log[s] = l0; s_log[SPAD + s] = l1;
            s_log[2 * SPAD + s] = l2; s_log[3 * SPAD + s] = l3;
        }
        __syncthreads();
        {
            const int d = d0 + wv;
            const float* row = s_log + wv * SPAD;
            const int s0 = lane, s1 = lane + 64, s2 = lane + 128;
            const float v0 = (s0 < NNODES && s0 != d) ? row[s0] : -1e30f;
            const float v1 = (s1 < NNODES && s1 != d) ? row[s1] : -1e30f;
            const float v2 = (s2 < NNODES && s2 != d) ? row[s2] : -1e30f;
            float mx = fmaxf(v0, fmaxf(v1, v2));
            mx = fmaxf(mx, __shfl_xor(mx, 32)); mx = fmaxf(mx, __shfl_xor(mx, 16));
            mx = fmaxf(mx, __shfl_xor(mx, 8));  mx = fmaxf(mx, __shfl_xor(mx, 4));
            mx = fmaxf(mx, __shfl_xor(mx, 2));  mx = fmaxf(mx, __shfl_xor(mx, 1));
            const float e0 = expf(v0 - mx), e1 = expf(v1 - mx), e2 = expf(v2 - mx);
            float zz = e0 + e1 + e2;
            zz += __shfl_xor(zz, 32); zz += __shfl_xor(zz, 16); zz += __shfl_xor(zz, 8);
            zz += __shfl_xor(zz, 4);  zz += __shfl_xor(zz, 2);  zz += __shfl_xor(zz, 1);
            const float sc = 0.25f / (zz + 1e-16f);
            if (d < NNODES) {
                float* arow = alphaR + ((size_t)(g * NH + h) * NNODES + d) * SPAD;
                if (s0 < NNODES) arow[s0] = e0 * sc;
                if (s1 < NNODES) arow[s1] = e1 * sc;
                if (s2 < NNODES) arow[s2] = e2 * sc;
            }
        }
    }
}

// ---------------------------------------------------------------- phase: aggregate
__device__ void agg_vb(char* smemraw, int vb,
    const float* alphaR, const float* xl, float* part)
{
    float* s_a = (float*)smemraw;       // 32*33
    float* s_x = s_a + 32 * 33;         // 32*64
    const int bx = vb % 6, by = (vb / 6) & 3, gh = vb / 24;
    const int g = gh >> 2, h = gh & 3;
    const int d0 = bx * 32, c0 = by * 64;
    const int tid = threadIdx.x;
    const int dr = (tid >> 4) * 2, cq = (tid & 15) * 4;
    const int sr = tid >> 3, sc4 = (tid & 7) * 4;
    const int xc8 = (tid & 7) * 8;

    float acc[2][4] = {{0.f,0.f,0.f,0.f},{0.f,0.f,0.f,0.f}};

    for (int s0 = 0; s0 < NNODES; s0 += 32) {
        __syncthreads();
        {
            const int d = d0 + sr;
            const float* ap = alphaR + ((size_t)gh * NNODES + d) * SPAD + s0 + sc4;
            const int ok = (d < NNODES);
            s_a[sr * 33 + sc4 + 0] = (ok && s0 + sc4 + 0 < NNODES) ? ap[0] : 0.f;
            s_a[sr * 33 + sc4 + 1] = (ok && s0 + sc4 + 1 < NNODES) ? ap[1] : 0.f;
            s_a[sr * 33 + sc4 + 2] = (ok && s0 + sc4 + 2 < NNODES) ? ap[2] : 0.f;
            s_a[sr * 33 + sc4 + 3] = (ok && s0 + sc4 + 3 < NNODES) ? ap[3] : 0.f;
        }
        {
            const int sg = s0 + sr;
            if (sg < NNODES) {
                const float* xp = xl + (size_t)(g * NNODES + sg) * (NH * CH) + h * CH + c0 + xc8;
                *(float4*)&s_x[sr * 64 + xc8]     = *(const float4*)(xp);
                *(float4*)&s_x[sr * 64 + xc8 + 4] = *(const float4*)(xp + 4);
            } else {
                #pragma unroll
                for (int j = 0; j < 8; j++) s_x[sr * 64 + xc8 + j] = 0.f;
            }
        }
        __syncthreads();
        #pragma unroll
        for (int k = 0; k < 32; k++) {
            const float a0 = s_a[(dr + 0) * 33 + k];
            const float a1 = s_a[(dr + 1) * 33 + k];
            const float4 xv = *(const float4*)&s_x[k * 64 + cq];
            acc[0][0] += a0 * xv.x; acc[0][1] += a0 * xv.y;
            acc[0][2] += a0 * xv.z; acc[0][3] += a0 * xv.w;
            acc[1][0] += a1 * xv.x; acc[1][1] += a1 * xv.y;
            acc[1][2] += a1 * xv.z; acc[1][3] += a1 * xv.w;
        }
    }
    #pragma unroll
    for (int i = 0; i < 2; i++) {
        const int d = d0 + dr + i;
        if (d >= NNODES) continue;
        float4 v;
        v.x = acc[i][0]; v.y = acc[i][1]; v.z = acc[i][2]; v.w = acc[i][3];
        *(float4*)(part + ((size_t)h * NNTOT + g * NNODES + d) * CH + c0 + cq) = v;
    }
}

// ---------------------------------------------------------------- phase: head-sum + LN
__device__ void ln_vb(char* smemraw, int node,
    const float* part, const void* bias, size_t oB,
    const void* ln_g, size_t oG, const void* ln_b, size_t oBt,
    float* h_out, int isbf)
{
    float* s_red = (float*)smemraw;   // 8
    const int c = threadIdx.x;
    const int lane = c & 63, wv = c >> 6;

    float vch = part[((size_t)0 * NNTOT + node) * CH + c]
              + part[((size_t)1 * NNTOT + node) * CH + c]
              + part[((size_t)2 * NNTOT + node) * CH + c]
              + part[((size_t)3 * NNTOT + node) * CH + c]
              + ldm(bias, oB + c, isbf);

    float s1 = vch, s2 = vch * vch;
    s1 += __shfl_xor(s1, 32); s2 += __shfl_xor(s2, 32);
    s1 += __shfl_xor(s1, 16); s2 += __shfl_xor(s2, 16);
    s1 += __shfl_xor(s1, 8);  s2 += __shfl_xor(s2, 8);
    s1 += __shfl_xor(s1, 4);  s2 += __shfl_xor(s2, 4);
    s1 += __shfl_xor(s1, 2);  s2 += __shfl_xor(s2, 2);
    s1 += __shfl_xor(s1, 1);  s2 += __shfl_xor(s2, 1);
    if (lane == 0) { s_red[wv] = s1; s_red[4 + wv] = s2; }
    __syncthreads();
    const float S1 = s_red[0] + s_red[1] + s_red[2] + s_red[3];
    const float S2 = s_red[4] + s_red[5] + s_red[6] + s_red[7];
    const float mu  = S1 * (1.f / CH);
    const float var = S2 * (1.f / CH) - mu * mu;
    const float o = (vch - mu) * rsqrtf(var + LN_EPS) * ldm(ln_g, oG + c, isbf)
                  + ldm(ln_b, oBt + c, isbf);
    h_out[(size_t)node * CH + c] = o;
}

// ---------------------------------------------------------------- the one kernel
__global__ __launch_bounds__(256) void k_all(
    const void* __restrict__ x_in,
    const void* __restrict__ Wl, const void* __restrict__ bl,
    const void* __restrict__ Wr, const void* __restrict__ br,
    const void* __restrict__ att, const void* __restrict__ bias,
    const void* __restrict__ lng, const void* __restrict__ lnb,
    const void* __restrict__ W1, const void* __restrict__ b1,
    const void* __restrict__ W2, const void* __restrict__ b2,
    float* __restrict__ xl, float* __restrict__ xr, float* __restrict__ xlT,
    float* __restrict__ alphaR, float* __restrict__ part,
    float* __restrict__ h_ln, float* __restrict__ m1,
    float* __restrict__ xa, float* __restrict__ xb,
    unsigned short* __restrict__ wlT, unsigned short* __restrict__ wrT,
    unsigned short* __restrict__ w1T, unsigned short* __restrict__ w2T,
    unsigned* __restrict__ bar, void* __restrict__ outp)
{
    __shared__ __align__(16) char smem[SMEMB];
    const int isbf = sniff_bf(lng);
    unsigned* cnt = bar;
    unsigned* gen = bar + 1;

    const size_t pLR  = (size_t)NL * (NH * CH) * CH;
    const size_t pM   = (size_t)NL * (2 * CH) * CH;
    const size_t lyLR = (size_t)(NH * CH) * CH;
    const size_t lyM  = (size_t)(2 * CH) * CH;

    // P0: weight prep
    wprep_phase(smem, Wl, Wr, W1, W2, wlT, wrT, w1T, w2T, isbf);
    gbar(cnt, gen);

    for (int l = 0; l < NL; l++) {
        const int israw = (l == 0);
        const int a_bf = israw ? isbf : 0;
        const void* xin = israw ? x_in : (const void*)((l == 1) ? xa : xb);
        float* xout = (l == 1) ? xb : xa;

        // P1: xl = x@Wl+bl (+xlT), xr = x@Wr+br
        for (int vb = blockIdx.x; vb < 352; vb += GRIDBLK) {
            const int bx = vb % 11, by = (vb / 11) & 15, z = vb / 176;
            gemm_vb(smem, bx * 32, by * 64, xin, a_bf, CH, NH * CH,
                    (z ? wrT : wlT) + l * lyLR,
                    (z ? wrT : wlT) + pLR + l * lyLR,
                    z ? br : bl, (size_t)l * (NH * CH), isbf,
                    nullptr, 0,
                    z ? xr : xl, z ? nullptr : xlT, 0);
        }
        gbar(cnt, gen);

        // P2: logits + softmax
        logits_phase(smem, xlT, xr, att, (size_t)l * (NH * CH), alphaR, isbf);
        gbar(cnt, gen);

        // P3: aggregate
        for (int vb = blockIdx.x; vb < 192; vb += GRIDBLK)
            agg_vb(smem, vb, alphaR, xl, part);
        gbar(cnt, gen);

        // P4: head-sum + LN
        for (int vb = blockIdx.x; vb < NNTOT; vb += GRIDBLK) {
            __syncthreads();
            ln_vb(smem, vb, part, bias, (size_t)l * CH,
                  lng, (size_t)l * CH, lnb, (size_t)l * CH, h_ln, isbf);
        }
        gbar(cnt, gen);

        // P5: m1 = relu(h_ln@W1+b1)
        for (int vb = blockIdx.x; vb < 88; vb += GRIDBLK)
            gemm_vb(smem, (vb % 11) * 32, (vb / 11) * 64, h_ln, 0, CH, 2 * CH,
                    w1T + l * lyM, w1T + pM + l * lyM,
                    b1, (size_t)l * (2 * CH), isbf,
                    nullptr, 0, m1, nullptr, 1);
        gbar(cnt, gen);

        // P6: x_next = x + m1@W2 + b2
        for (int vb = blockIdx.x; vb < 44; vb += GRIDBLK)
            gemm_vb(smem, (vb % 11) * 32, (vb / 11) * 64, m1, 0, 2 * CH, CH,
                    w2T + l * lyM, w2T + pM + l * lyM,
                    b2, (size_t)l * CH, isbf,
                    xin, a_bf, xout, nullptr, 2);
        gbar(cnt, gen);
    }

    // pool (x final = xa)
    for (int vb = blockIdx.x; vb < 2; vb += GRIDBLK) {
        const int g = vb, c = threadIdx.x;
        float s = 0.f;
        const float* p = xa + (size_t)g * NNODES * CH + c;
        for (int n = 0; n < NNODES; n++) s += p[(size_t)n * CH];
        const float v = s * (1.f / NNODES);
        if (isbf) ((bf16*)outp)[g * CH + c] = __float2bfloat16(v);
        else      ((float*)outp)[g * CH + c] = v;
    }
}

// ---------------------------------------------------------------- launch
extern "C" void kernel_launch(void* const* d_in, const int* in_sizes, int n_in,
                              void* d_out, int out_size, void* d_ws, size_t ws_size,
                              hipStream_t stream)
{
    const void* x_in = d_in[0];
    const void* Wl   = d_in[1];
    const void* bl   = d_in[2];
    const void* Wr   = d_in[3];
    const void* br   = d_in[4];
    const void* att  = d_in[5];
    const void* bias = d_in[6];
    const void* lng  = d_in[7];
    const void* lnb  = d_in[8];
    const void* W1   = d_in[9];
    const void* b1   = d_in[10];
    const void* W2   = d_in[11];
    const void* b2   = d_in[12];

    float* ws     = (float*)d_ws;
    float* xl     = ws;
    float* xr     = xl + (size_t)NNTOT * NH * CH;
    float* xlT    = xr + (size_t)NNTOT * NH * CH;
    float* alphaR = xlT + (size_t)2 * NH * CH * SPAD;
    float* part   = alphaR + (size_t)2 * NH * NNODES * SPAD;
    float* h_ln   = part + (size_t)NH * NNTOT * CH;
    float* m1     = h_ln + (size_t)NNTOT * CH;
    float* xa     = m1 + (size_t)NNTOT * 2 * CH;
    float* xb     = xa + (size_t)NNTOT * CH;

    unsigned short* wbt = (unsigned short*)(xb + (size_t)NNTOT * CH);
    const size_t pLR = (size_t)NL * (NH * CH) * CH;
    const size_t pM  = (size_t)NL * (2 * CH) * CH;
    unsigned short* wlT = wbt;
    unsigned short* wrT = wlT + 2 * pLR;
    unsigned short* w1T = wrT + 2 * pLR;
    unsigned short* w2T = w1T + 2 * pM;
    unsigned* bar = (unsigned*)(w2T + 2 * pM);

    hipMemsetAsync(bar, 0, 16, stream);

    k_all<<<dim3(GRIDBLK), dim3(256), 0, stream>>>(
        x_in, Wl, bl, Wr, br, att, bias, lng, lnb, W1, b1, W2, b2,
        xl, xr, xlT, alphaR, part, h_ln, m1, xa, xb,
        wlT, wrT, w1T, w2T, bar, d_out);
}

// Round 3
// 327.961 us; speedup vs baseline: 4.2400x; 4.2400x over previous
//
#include <hip/hip_runtime.h>
#include <hip/hip_bf16.h>

typedef __hip_bfloat16 bf16;
typedef __attribute__((ext_vector_type(4))) float f32x4;
typedef __attribute__((ext_vector_type(8))) unsigned short u16x8;
typedef __attribute__((ext_vector_type(4))) unsigned short u16x4;
typedef __bf16 bf16x8 __attribute__((ext_vector_type(8)));

#define NNODES 169
#define NNTOT  338
#define CH     256
#define NH     4
#define NL     3
#define SPAD   176
#define LN_EPS 1e-5f

__device__ __forceinline__ float b2f(bf16 v) { return __bfloat162float(v); }
__device__ __forceinline__ float lrelu(float v) { return fmaxf(v, 0.2f * v); }
__device__ __forceinline__ float ldm(const void* p, size_t i, int isbf) {
    return isbf ? b2f(((const bf16*)p)[i]) : ((const float*)p)[i];
}
__device__ __forceinline__ int sniff_bf(const void* lng) {
    return ((((const unsigned*)lng)[0] & 0xFFFFu) == 0x3F80u) ? 1 : 0;
}
__device__ __forceinline__ unsigned short f2bf_rn(float f) {
    unsigned u = __float_as_uint(f);
    u += 0x7FFFu + ((u >> 16) & 1u);
    return (unsigned short)(u >> 16);
}
__device__ __forceinline__ float bfb2f(unsigned short h) {
    return __uint_as_float(((unsigned)h) << 16);
}

// ---------------------------------------------------------------- W prep
// Transpose + bf16-hi/lo split of all weights, once per launch.
// Output per family: hi plane [L][N][K] then lo plane [L][N][K] (bf16 bits).
__global__ __launch_bounds__(256) void k_wprep(
    const void* __restrict__ Wl, const void* __restrict__ Wr,
    const void* __restrict__ W1, const void* __restrict__ W2,
    unsigned short* __restrict__ wlT, unsigned short* __restrict__ wrT,
    unsigned short* __restrict__ w1T, unsigned short* __restrict__ w2T,
    const void* __restrict__ lng)
{
    __shared__ unsigned short sH[64 * 72];
    __shared__ unsigned short sL[64 * 72];
    const int isbf = sniff_bf(lng);
    int t = blockIdx.x;
    const void* src; unsigned short* dst; int K, N;
    if (t < 384)      { K = 256; N = 1024; src = (t < 192) ? Wl : Wr;
                        dst = (t < 192) ? wlT : wrT; t = t % 192; }
    else if (t < 480) { K = 256; N = 512;  src = W1; dst = w1T; t -= 384; }
    else              { K = 512; N = 256;  src = W2; dst = w2T; t -= 480; }
    const int ntiles = N / 64;
    const int tpl = (K / 64) * ntiles;
    const int l = t / tpl; t %= tpl;
    const int k0 = (t / ntiles) * 64, n0 = (t % ntiles) * 64;
    const size_t loPlane = (size_t)NL * K * N;
    const int tid = threadIdx.x;

    const int kk = tid >> 2, q = tid & 3;
    if (isbf) {
        const bf16* srow = (const bf16*)src + ((size_t)l * K + k0 + kk) * N + n0;
        #pragma unroll
        for (int i = 0; i < 4; i++) {
            const int c = q * 4 + i * 16;
            const int2 w = *(const int2*)(srow + c);
            sH[kk * 72 + c + 0] = (unsigned short)(w.x & 0xFFFF);
            sH[kk * 72 + c + 1] = (unsigned short)(((unsigned)w.x) >> 16);
            sH[kk * 72 + c + 2] = (unsigned short)(w.y & 0xFFFF);
            sH[kk * 72 + c + 3] = (unsigned short)(((unsigned)w.y) >> 16);
            sL[kk * 72 + c + 0] = 0; sL[kk * 72 + c + 1] = 0;
            sL[kk * 72 + c + 2] = 0; sL[kk * 72 + c + 3] = 0;
        }
    } else {
        const float* srow = (const float*)src + ((size_t)l * K + k0 + kk) * N + n0;
        #pragma unroll
        for (int i = 0; i < 4; i++) {
            const int c = q * 4 + i * 16;
            const float4 v4 = *(const float4*)(srow + c);
            const float vv[4] = { v4.x, v4.y, v4.z, v4.w };
            #pragma unroll
            for (int j = 0; j < 4; j++) {
                const unsigned short h = f2bf_rn(vv[j]);
                sH[kk * 72 + c + j] = h;
                sL[kk * 72 + c + j] = f2bf_rn(vv[j] - bfb2f(h));
            }
        }
    }
    __syncthreads();
    for (int u = tid; u < 512; u += 256) {
        const int n = u >> 3, k8 = (u & 7) * 8;
        u16x8 hh, ll;
        #pragma unroll
        for (int j = 0; j < 8; j++) {
            hh[j] = sH[(k8 + j) * 72 + n];
            ll[j] = sL[(k8 + j) * 72 + n];
        }
        unsigned short* dh = dst + ((size_t)l * N + n0 + n) * K + k0 + k8;
        *(u16x8*)dh = hh;
        *(u16x8*)(dh + loPlane) = ll;
    }
}

// ---------------------------------------------------------------- unified MFMA GEMM
// C[338 x N] = A[338 x K] @ W + epilogue; bf16x3 split; tile 32x64, 4 waves.
// mode 0: +bias -> out (xl/xr via z; z==0 also scatters xlT)
// mode 2: +bias + residual -> out
__global__ __launch_bounds__(256) void k_gemm_mfma(
    const void* __restrict__ A, int a_raw, int K, int N,
    const unsigned short* __restrict__ wH0, const unsigned short* __restrict__ wL0,
    const unsigned short* __restrict__ wH1, const unsigned short* __restrict__ wL1,
    const void* __restrict__ bias0, const void* __restrict__ bias1, size_t oB,
    const void* __restrict__ res, int r_raw,
    float* __restrict__ out0, float* __restrict__ out1,
    float* __restrict__ xlT, int mode, const void* __restrict__ lng)
{
    __shared__ unsigned short sAh[32 * 40], sAl[32 * 40];
    __shared__ unsigned short sBh[64 * 40], sBl[64 * 40];
    const int isbf = sniff_bf(lng);
    const int z = blockIdx.z;
    const unsigned short* wH = z ? wH1 : wH0;
    const unsigned short* wL = z ? wL1 : wL0;
    const void* bias = z ? bias1 : bias0;
    float* out = z ? out1 : out0;
    const int a_bf = a_raw ? isbf : 0;
    const int tid = threadIdx.x;
    const int wave = tid >> 6, lane = tid & 63, l15 = lane & 15, g = lane >> 4;
    const int m0 = blockIdx.x * 32, n0 = blockIdx.y * 64;

    const int ar = tid >> 3, ak = (tid & 7) * 4;
    const int bn = tid >> 2, boct = tid & 3;

    f32x4 acc0 = {0.f, 0.f, 0.f, 0.f};
    f32x4 acc1 = {0.f, 0.f, 0.f, 0.f};
    const float* Af = (const float*)A;

    for (int k0 = 0; k0 < K; k0 += 32) {
        unsigned short h4[4] = {0, 0, 0, 0}, l4[4] = {0, 0, 0, 0};
        {
            const int grow = m0 + ar;
            if (grow < NNTOT) {
                const size_t ai = (size_t)grow * K + k0 + ak;
                if (a_bf) {
                    const int2 w = *(const int2*)((const bf16*)A + ai);
                    h4[0] = (unsigned short)(w.x & 0xFFFF);
                    h4[1] = (unsigned short)(((unsigned)w.x) >> 16);
                    h4[2] = (unsigned short)(w.y & 0xFFFF);
                    h4[3] = (unsigned short)(((unsigned)w.y) >> 16);
                } else {
                    const float4 t = *(const float4*)(Af + ai);
                    const float vv[4] = { t.x, t.y, t.z, t.w };
                    #pragma unroll
                    for (int j = 0; j < 4; j++) {
                        h4[j] = f2bf_rn(vv[j]);
                        l4[j] = f2bf_rn(vv[j] - bfb2f(h4[j]));
                    }
                }
            }
        }
        const size_t bi = (size_t)(n0 + bn) * K + k0 + boct * 8;
        const u16x8 bhv = *(const u16x8*)(wH + bi);
        const u16x8 blv = *(const u16x8*)(wL + bi);
        __syncthreads();
        {
            u16x4 ha, la;
            ha[0] = h4[0]; ha[1] = h4[1]; ha[2] = h4[2]; ha[3] = h4[3];
            la[0] = l4[0]; la[1] = l4[1]; la[2] = l4[2]; la[3] = l4[3];
            *(u16x4*)&sAh[ar * 40 + ak] = ha;
            *(u16x4*)&sAl[ar * 40 + ak] = la;
            *(u16x8*)&sBh[bn * 40 + boct * 8] = bhv;
            *(u16x8*)&sBl[bn * 40 + boct * 8] = blv;
        }
        __syncthreads();
        const bf16x8 a_h0 = *(const bf16x8*)&sAh[l15 * 40 + g * 8];
        const bf16x8 a_h1 = *(const bf16x8*)&sAh[(16 + l15) * 40 + g * 8];
        const bf16x8 a_l0 = *(const bf16x8*)&sAl[l15 * 40 + g * 8];
        const bf16x8 a_l1 = *(const bf16x8*)&sAl[(16 + l15) * 40 + g * 8];
        const bf16x8 b_h  = *(const bf16x8*)&sBh[(wave * 16 + l15) * 40 + g * 8];
        const bf16x8 b_l  = *(const bf16x8*)&sBl[(wave * 16 + l15) * 40 + g * 8];
        acc0 = __builtin_amdgcn_mfma_f32_16x16x32_bf16(a_h0, b_h, acc0, 0, 0, 0);
        acc1 = __builtin_amdgcn_mfma_f32_16x16x32_bf16(a_h1, b_h, acc1, 0, 0, 0);
        acc0 = __builtin_amdgcn_mfma_f32_16x16x32_bf16(a_l0, b_h, acc0, 0, 0, 0);
        acc1 = __builtin_amdgcn_mfma_f32_16x16x32_bf16(a_l1, b_h, acc1, 0, 0, 0);
        acc0 = __builtin_amdgcn_mfma_f32_16x16x32_bf16(a_h0, b_l, acc0, 0, 0, 0);
        acc1 = __builtin_amdgcn_mfma_f32_16x16x32_bf16(a_h1, b_l, acc1, 0, 0, 0);
    }

    const int col = n0 + wave * 16 + l15;
    const float bv = ldm(bias, oB + col, isbf);
    #pragma unroll
    for (int mi = 0; mi < 2; mi++) {
        const f32x4 a = mi ? acc1 : acc0;
        #pragma unroll
        for (int r = 0; r < 4; r++) {
            const int row = m0 + mi * 16 + g * 4 + r;
            if (row >= NNTOT) continue;
            float v = a[r] + bv;
            if (mode == 2) v += ldm(res, (size_t)row * N + col, r_raw ? isbf : 0);
            out[(size_t)row * N + col] = v;
            if (mode == 0 && z == 0) {
                const int hh = col >> 8, cc = col & 255;
                const int gg = (row >= NNODES) ? 1 : 0;
                const int ss = row - gg * NNODES;
                xlT[((size_t)(gg * NH + hh) * CH + cc) * SPAD + ss] = v;
            }
        }
    }
}

// ---------------------------------------------------------------- fused attn:
// logits + softmax + aggregation. grid (43, NH, 2): block owns 4 targets of one
// (g,h). Alpha rows (0.25/z folded) stay in LDS; aggregation writes part directly.
__global__ __launch_bounds__(256) void k_attn(
    const float* __restrict__ xlT, const float* __restrict__ xr,
    const float* __restrict__ xl,
    const void* __restrict__ att, size_t oA,
    float* __restrict__ part, const void* __restrict__ lng)
{
    __shared__ float s_att[CH];
    __shared__ float s_xr[4 * CH];
    __shared__ float s_tile[32 * SPAD];
    __shared__ float s_log[4 * SPAD];
    const int isbf = sniff_bf(lng);
    const int g = blockIdx.z, h = blockIdx.y, d0 = blockIdx.x * 4;
    const int tid = threadIdx.x, lane = tid & 63, wv = tid >> 6;

    s_att[tid] = ldm(att, oA + h * CH + tid, isbf);
    for (int idx = tid; idx < 4 * CH; idx += 256) {
        const int i = idx >> 8, c = idx & 255, d = d0 + i;
        s_xr[idx] = (d < NNODES)
            ? xr[(size_t)(g * NNODES + d) * (NH * CH) + h * CH + c] : 0.f;
    }

    float l0 = 0.f, l1 = 0.f, l2 = 0.f, l3 = 0.f;
    const int s = tid;
    const float4* src = (const float4*)(xlT + ((size_t)(g * NH + h) * CH) * SPAD);
    for (int ch = 0; ch < 8; ch++) {
        __syncthreads();
        for (int i = tid; i < 32 * SPAD / 4; i += 256)
            ((float4*)s_tile)[i] = src[ch * (32 * SPAD / 4) + i];
        __syncthreads();
        if (s < NNODES) {
            const int cb = ch * 32;
            #pragma unroll
            for (int c = 0; c < 32; c++) {
                const float v = s_tile[c * SPAD + s];
                const float a = s_att[cb + c];
                l0 += a * lrelu(v + s_xr[cb + c]);
                l1 += a * lrelu(v + s_xr[CH + cb + c]);
                l2 += a * lrelu(v + s_xr[2 * CH + cb + c]);
                l3 += a * lrelu(v + s_xr[3 * CH + cb + c]);
            }
        }
    }
    if (s < NNODES) {
        s_log[s] = l0; s_log[SPAD + s] = l1;
        s_log[2 * SPAD + s] = l2; s_log[3 * SPAD + s] = l3;
    }
    __syncthreads();
    {   // softmax for row wv; alpha written back in place (scaled 0.25/z)
        const int d = d0 + wv;
        float* row = s_log + wv * SPAD;
        const int s0 = lane, s1 = lane + 64, s2 = lane + 128;
        const float v0 = (s0 < NNODES && s0 != d) ? row[s0] : -1e30f;
        const float v1 = (s1 < NNODES && s1 != d) ? row[s1] : -1e30f;
        const float v2 = (s2 < NNODES && s2 != d) ? row[s2] : -1e30f;
        float mx = fmaxf(v0, fmaxf(v1, v2));
        mx = fmaxf(mx, __shfl_xor(mx, 32)); mx = fmaxf(mx, __shfl_xor(mx, 16));
        mx = fmaxf(mx, __shfl_xor(mx, 8));  mx = fmaxf(mx, __shfl_xor(mx, 4));
        mx = fmaxf(mx, __shfl_xor(mx, 2));  mx = fmaxf(mx, __shfl_xor(mx, 1));
        const float e0 = expf(v0 - mx), e1 = expf(v1 - mx), e2 = expf(v2 - mx);
        float zz = e0 + e1 + e2;
        zz += __shfl_xor(zz, 32); zz += __shfl_xor(zz, 16); zz += __shfl_xor(zz, 8);
        zz += __shfl_xor(zz, 4);  zz += __shfl_xor(zz, 2);  zz += __shfl_xor(zz, 1);
        const float sc = 0.25f / (zz + 1e-16f);
        row[s0] = (s0 < NNODES) ? e0 * sc : 0.f;
        row[s1] = (s1 < NNODES) ? e1 * sc : 0.f;
        if (s2 < SPAD) row[s2] = (s2 < NNODES) ? e2 * sc : 0.f;
    }
    __syncthreads();

    // aggregation: thread owns channel c; 4 target accumulators
    const int c = tid;
    float a0 = 0.f, a1 = 0.f, a2 = 0.f, a3 = 0.f;
    const float* xbase = xl + (size_t)g * NNODES * (NH * CH) + h * CH + c;
    for (int s4 = 0; s4 < 168; s4 += 4) {
        const float4 q0 = *(const float4*)&s_log[s4];
        const float4 q1 = *(const float4*)&s_log[SPAD + s4];
        const float4 q2 = *(const float4*)&s_log[2 * SPAD + s4];
        const float4 q3 = *(const float4*)&s_log[3 * SPAD + s4];
        const float x0 = xbase[(size_t)(s4 + 0) * (NH * CH)];
        const float x1 = xbase[(size_t)(s4 + 1) * (NH * CH)];
        const float x2 = xbase[(size_t)(s4 + 2) * (NH * CH)];
        const float x3 = xbase[(size_t)(s4 + 3) * (NH * CH)];
        a0 += q0.x * x0 + q0.y * x1 + q0.z * x2 + q0.w * x3;
        a1 += q1.x * x0 + q1.y * x1 + q1.z * x2 + q1.w * x3;
        a2 += q2.x * x0 + q2.y * x1 + q2.z * x2 + q2.w * x3;
        a3 += q3.x * x0 + q3.y * x1 + q3.z * x2 + q3.w * x3;
    }
    {
        const float x0 = xbase[(size_t)168 * (NH * CH)];
        a0 += s_log[168] * x0;            a1 += s_log[SPAD + 168] * x0;
        a2 += s_log[2 * SPAD + 168] * x0; a3 += s_log[3 * SPAD + 168] * x0;
    }
    const float av[4] = { a0, a1, a2, a3 };
    #pragma unroll
    for (int i = 0; i < 4; i++) {
        const int d = d0 + i;
        if (d < NNODES)
            part[((size_t)h * NNTOT + g * NNODES + d) * CH + c] = av[i];
    }
}

// ---------------------------------------------------------------- fused LN + MLP1
// Block: 32 rows x 64 cols of m1 = relu(LN(head-sum(part)+bias) @ W1 + b1).
// LN computed in-block (wave-per-row), written as bf16 hi/lo A-tile to LDS.
__global__ __launch_bounds__(256) void k_lnmlp1(
    const float* __restrict__ part,
    const void* __restrict__ bias, size_t oB,
    const void* __restrict__ ln_g, size_t oG,
    const void* __restrict__ ln_b, size_t oBt,
    const unsigned short* __restrict__ wH, const unsigned short* __restrict__ wL,
    const void* __restrict__ b1, size_t oB1,
    float* __restrict__ m1, const void* __restrict__ lng)
{
    __shared__ unsigned short sAh[32 * 264], sAl[32 * 264];
    __shared__ unsigned short sBh[64 * 40], sBl[64 * 40];
    __shared__ float sPar[3 * CH];
    const int isbf = sniff_bf(lng);
    const int tid = threadIdx.x;
    const int wave = tid >> 6, lane = tid & 63, l15 = lane & 15, g = lane >> 4;
    const int m0 = blockIdx.x * 32, n0 = blockIdx.y * 64;

    sPar[tid]          = ldm(bias, oB + tid, isbf);
    sPar[CH + tid]     = ldm(ln_g, oG + tid, isbf);
    sPar[2 * CH + tid] = ldm(ln_b, oBt + tid, isbf);
    __syncthreads();

    const int c4 = lane * 4;
    #pragma unroll
    for (int rr = 0; rr < 8; rr++) {
        const int r = wave + rr * 4;
        const int gr = m0 + r;
        u16x4 hq = {0, 0, 0, 0}, lq = {0, 0, 0, 0};
        if (gr < NNTOT) {
            const float4 p0 = *(const float4*)(part + ((size_t)0 * NNTOT + gr) * CH + c4);
            const float4 p1 = *(const float4*)(part + ((size_t)1 * NNTOT + gr) * CH + c4);
            const float4 p2 = *(const float4*)(part + ((size_t)2 * NNTOT + gr) * CH + c4);
            const float4 p3 = *(const float4*)(part + ((size_t)3 * NNTOT + gr) * CH + c4);
            float v[4] = { p0.x + p1.x + p2.x + p3.x + sPar[c4 + 0],
                           p0.y + p1.y + p2.y + p3.y + sPar[c4 + 1],
                           p0.z + p1.z + p2.z + p3.z + sPar[c4 + 2],
                           p0.w + p1.w + p2.w + p3.w + sPar[c4 + 3] };
            float s1 = v[0] + v[1] + v[2] + v[3];
            float s2 = v[0]*v[0] + v[1]*v[1] + v[2]*v[2] + v[3]*v[3];
            s1 += __shfl_xor(s1, 32); s2 += __shfl_xor(s2, 32);
            s1 += __shfl_xor(s1, 16); s2 += __shfl_xor(s2, 16);
            s1 += __shfl_xor(s1, 8);  s2 += __shfl_xor(s2, 8);
            s1 += __shfl_xor(s1, 4);  s2 += __shfl_xor(s2, 4);
            s1 += __shfl_xor(s1, 2);  s2 += __shfl_xor(s2, 2);
            s1 += __shfl_xor(s1, 1);  s2 += __shfl_xor(s2, 1);
            const float mu  = s1 * (1.f / CH);
            const float var = s2 * (1.f / CH) - mu * mu;
            const float rs  = rsqrtf(var + LN_EPS);
            #pragma unroll
            for (int j = 0; j < 4; j++) {
                const float o = (v[j] - mu) * rs * sPar[CH + c4 + j] + sPar[2 * CH + c4 + j];
                const unsigned short hh = f2bf_rn(o);
                hq[j] = hh;
                lq[j] = f2bf_rn(o - bfb2f(hh));
            }
        }
        *(u16x4*)&sAh[r * 264 + c4] = hq;
        *(u16x4*)&sAl[r * 264 + c4] = lq;
    }

    const int bn = tid >> 2, boct = tid & 3;
    f32x4 acc0 = {0.f, 0.f, 0.f, 0.f};
    f32x4 acc1 = {0.f, 0.f, 0.f, 0.f};
    for (int k0 = 0; k0 < CH; k0 += 32) {
        const size_t bi = (size_t)(n0 + bn) * CH + k0 + boct * 8;
        const u16x8 bhv = *(const u16x8*)(wH + bi);
        const u16x8 blv = *(const u16x8*)(wL + bi);
        __syncthreads();
        *(u16x8*)&sBh[bn * 40 + boct * 8] = bhv;
        *(u16x8*)&sBl[bn * 40 + boct * 8] = blv;
        __syncthreads();
        const bf16x8 a_h0 = *(const bf16x8*)&sAh[l15 * 264 + k0 + g * 8];
        const bf16x8 a_h1 = *(const bf16x8*)&sAh[(16 + l15) * 264 + k0 + g * 8];
        const bf16x8 a_l0 = *(const bf16x8*)&sAl[l15 * 264 + k0 + g * 8];
        const bf16x8 a_l1 = *(const bf16x8*)&sAl[(16 + l15) * 264 + k0 + g * 8];
        const bf16x8 b_h  = *(const bf16x8*)&sBh[(wave * 16 + l15) * 40 + g * 8];
        const bf16x8 b_l  = *(const bf16x8*)&sBl[(wave * 16 + l15) * 40 + g * 8];
        acc0 = __builtin_amdgcn_mfma_f32_16x16x32_bf16(a_h0, b_h, acc0, 0, 0, 0);
        acc1 = __builtin_amdgcn_mfma_f32_16x16x32_bf16(a_h1, b_h, acc1, 0, 0, 0);
        acc0 = __builtin_amdgcn_mfma_f32_16x16x32_bf16(a_l0, b_h, acc0, 0, 0, 0);
        acc1 = __builtin_amdgcn_mfma_f32_16x16x32_bf16(a_l1, b_h, acc1, 0, 0, 0);
        acc0 = __builtin_amdgcn_mfma_f32_16x16x32_bf16(a_h0, b_l, acc0, 0, 0, 0);
        acc1 = __builtin_amdgcn_mfma_f32_16x16x32_bf16(a_h1, b_l, acc1, 0, 0, 0);
    }

    const int col = n0 + wave * 16 + l15;
    const float bv = ldm(b1, oB1 + col, isbf);
    #pragma unroll
    for (int mi = 0; mi < 2; mi++) {
        const f32x4 a = mi ? acc1 : acc0;
        #pragma unroll
        for (int r = 0; r < 4; r++) {
            const int row = m0 + mi * 16 + g * 4 + r;
            if (row >= NNTOT) continue;
            m1[(size_t)row * (2 * CH) + col] = fmaxf(a[r] + bv, 0.f);
        }
    }
}

// ---------------------------------------------------------------- pool
__global__ __launch_bounds__(256) void k_pool(const float* __restrict__ x,
                                              void* __restrict__ out,
                                              const void* __restrict__ lng) {
    const int isbf = sniff_bf(lng);
    const int g = blockIdx.x, c = threadIdx.x;
    float s = 0.f;
    const float* p = x + (size_t)g * NNODES * CH + c;
    for (int n = 0; n < NNODES; n++) s += p[(size_t)n * CH];
    const float v = s * (1.f / NNODES);
    if (isbf) ((bf16*)out)[g * CH + c] = __float2bfloat16(v);
    else      ((float*)out)[g * CH + c] = v;
}

// ---------------------------------------------------------------- launch
extern "C" void kernel_launch(void* const* d_in, const int* in_sizes, int n_in,
                              void* d_out, int out_size, void* d_ws, size_t ws_size,
                              hipStream_t stream)
{
    const void* x_in = d_in[0];
    const void* Wl   = d_in[1];
    const void* bl   = d_in[2];
    const void* Wr   = d_in[3];
    const void* br   = d_in[4];
    const void* att  = d_in[5];
    const void* bias = d_in[6];
    const void* lng  = d_in[7];
    const void* lnb  = d_in[8];
    const void* W1   = d_in[9];
    const void* b1   = d_in[10];
    const void* W2   = d_in[11];
    const void* b2   = d_in[12];

    float* ws     = (float*)d_ws;
    float* xl     = ws;                                      // 338*1024
    float* xr     = xl + (size_t)NNTOT * NH * CH;            // 338*1024
    float* xlT    = xr + (size_t)NNTOT * NH * CH;            // 2*4*256*176
    float* part   = xlT + (size_t)2 * NH * CH * SPAD;        // 4*338*256
    float* m1     = part + (size_t)NH * NNTOT * CH;          // 338*512
    float* xa     = m1 + (size_t)NNTOT * 2 * CH;             // 338*256
    float* xb     = xa + (size_t)NNTOT * CH;                 // 338*256

    unsigned short* wbt = (unsigned short*)(xb + (size_t)NNTOT * CH);
    const size_t pLR = (size_t)NL * (NH * CH) * CH;
    const size_t pM  = (size_t)NL * (2 * CH) * CH;
    unsigned short* wlT = wbt;
    unsigned short* wrT = wlT + 2 * pLR;
    unsigned short* w1T = wrT + 2 * pLR;
    unsigned short* w2T = w1T + 2 * pM;
    const size_t lyLR = (size_t)(NH * CH) * CH;
    const size_t lyM  = (size_t)(2 * CH) * CH;

    const void* x_l[3] = { x_in, xa, xb };
    float*      x_o[3] = { xa, xb, xa };

    k_wprep<<<dim3(576), 256, 0, stream>>>(Wl, Wr, W1, W2, wlT, wrT, w1T, w2T, lng);

    for (int l = 0; l < NL; l++) {
        const int israw = (l == 0);
        // P1: xl = x@Wl+bl (+xlT), xr = x@Wr+br
        k_gemm_mfma<<<dim3(11, 16, 2), 256, 0, stream>>>(
            x_l[l], israw, CH, NH * CH,
            wlT + l * lyLR, wlT + pLR + l * lyLR,
            wrT + l * lyLR, wrT + pLR + l * lyLR,
            bl, br, (size_t)l * (NH * CH),
            nullptr, 0,
            xl, xr, xlT, 0, lng);
        // P2: logits + softmax + aggregate -> part
        k_attn<<<dim3(43, NH, 2), 256, 0, stream>>>(
            xlT, xr, xl, att, (size_t)l * (NH * CH), part, lng);
        // P3: head-sum + LN + MLP1 -> m1
        k_lnmlp1<<<dim3(11, 8), 256, 0, stream>>>(
            part, bias, (size_t)l * CH, lng, (size_t)l * CH, lnb, (size_t)l * CH,
            w1T + l * lyM, w1T + pM + l * lyM,
            b1, (size_t)l * (2 * CH), m1, lng);
        // P4: x_next = x + m1@W2 + b2
        k_gemm_mfma<<<dim3(11, 4, 1), 256, 0, stream>>>(
            m1, 0, 2 * CH, CH,
            w2T + l * lyM, w2T + pM + l * lyM,
            w2T + l * lyM, w2T + pM + l * lyM,
            b2, b2, (size_t)l * CH,
            x_l[l], israw,
            x_o[l], x_o[l], nullptr, 2, lng);
    }

    k_pool<<<dim3(2), 256, 0, stream>>>(xa, d_out, lng);
}